// Round 15
// baseline (104.158 us; speedup 1.0000x reference)
//
#include <hip/hip_runtime.h>

#define SEQ 2048
#define DIM 1280
#define NH 16
#define HD 80

typedef __attribute__((ext_vector_type(8))) short short8;
typedef __attribute__((ext_vector_type(4))) float f32x4;
typedef unsigned short u16;

__device__ inline u16 f2bf(float f) {
  unsigned u = __builtin_bit_cast(unsigned, f);
  u += 0x7FFFu + ((u >> 16) & 1u);
  return (u16)(u >> 16);
}
__device__ inline float bf2f(u16 h) {
  unsigned u = ((unsigned)h) << 16;
  return __builtin_bit_cast(float, u);
}

// async global->LDS, 16B per lane, dest = wave-uniform base + lane*16
#define GLOAD16(gsrc, ldst)                                                          \
  __builtin_amdgcn_global_load_lds((const __attribute__((address_space(1))) unsigned*)(gsrc), \
                                   (__attribute__((address_space(3))) unsigned*)(ldst), 16, 0, 0)

// acquire: own in-flight loads drained (aged one full step -> ~free), then
// block-wide barrier; sched_barrier pins everything below it.
#define ACQUIRE()                                  \
  asm volatile("s_waitcnt vmcnt(0)" ::: "memory"); \
  __builtin_amdgcn_s_barrier();                    \
  __builtin_amdgcn_sched_barrier(0)

// ---------------- all f32 -> bf16 conversions in one launch ----------------
__global__ void cvt5(const float* __restrict__ s0, const float* __restrict__ s1,
                     const float* __restrict__ s2, const float* __restrict__ s3,
                     const float* __restrict__ s4, u16* __restrict__ hs_b,
                     u16* __restrict__ w_b, int nh, int nw) {
  int y = blockIdx.y;
  const float* src = y == 0 ? s0 : (y == 1 ? s1 : (y == 2 ? s2 : (y == 3 ? s3 : s4)));
  int n = y == 0 ? nh : nw;
  u16* dst = y == 0 ? hs_b : w_b + (long)(y - 1) * nw;
  int i = (blockIdx.x * 256 + threadIdx.x) * 4;
  if (i >= n) return;
  float4 v = *(const float4*)(src + i);
  ushort4 pk;
  pk.x = f2bf(v.x); pk.y = f2bf(v.y); pk.z = f2bf(v.z); pk.w = f2bf(v.w);
  *(ushort4*)(dst + i) = pk;
}

// ------------- QKV GEMM: 256x256 tile, BK=64, 8 waves (128x64 each, 8x4) ----
// MFMA-bound shape: 6B/lane/MFMA fragment economy (2x better than 128x128
// 8-wave). 120 blocks (1/CU, 47% CUs idle) but ~2x per-CU efficiency.
// Same verified 1-barrier ACQUIRE protocol + XOR swizzle as R10.
__global__ __launch_bounds__(512) void gemm_qkv128(
    const u16* __restrict__ A, const u16* __restrict__ B,
    const float* __restrict__ b0, const float* __restrict__ b1,
    const float* __restrict__ b2, u16* __restrict__ outQ, u16* __restrict__ outK,
    u16* __restrict__ outVT) {
  __shared__ u16 As[2][256 * 64];   // 64 KB
  __shared__ u16 Bs[2][256 * 64];   // 64 KB
  const int K = DIM;
  const int tid = threadIdx.x;
  const int wave = tid >> 6, lane = tid & 63;
  const int lrow = lane & 15, lgrp = lane >> 4;
  const int wr = (wave >> 2) * 128, wc = (wave & 3) * 64;

  // XCD swizzle: 120 blocks, 15 per XCD chunk; A-panel resident per chunk
  const int lid = blockIdx.x;
  const int wg = (lid & 7) * 15 + (lid >> 3);
  const int bm = wg / 15, bn = wg % 15;  // 8 M-blocks, 15 N-blocks

  // staging: A = 2048 chunks (4/thread), B = 2048 chunks (4/thread)
  int rowS[4], offS[4];
#pragma unroll
  for (int j = 0; j < 4; j++) {
    int cid = j * 512 + tid;
    rowS[j] = cid >> 3;
    offS[j] = ((cid & 7) ^ (rowS[j] & 7)) * 8;
  }
  const u16* Abase = A + (long)bm * 256 * K;
  const u16* Bbase = B + (long)bn * 256 * K;

  f32x4 acc[8][4] = {};
  const int NT = K >> 6;  // 20

#define QKV_STAGE(buf, k0)                                                         \
  {                                                                                \
    _Pragma("unroll") for (int j = 0; j < 4; j++)                                  \
        GLOAD16(Abase + (long)rowS[j] * K + (k0) + offS[j],                        \
                &As[buf][(j * 512 + wave * 64) * 8]);                              \
    _Pragma("unroll") for (int j = 0; j < 4; j++)                                  \
        GLOAD16(Bbase + (long)rowS[j] * K + (k0) + offS[j],                        \
                &Bs[buf][(j * 512 + wave * 64) * 8]);                              \
  }

  QKV_STAGE(0, 0);

  for (int t = 0; t < NT; t++) {
    const int cur = t & 1;
    ACQUIRE();  // cur's loads landed everywhere; prev reads done everywhere
    if (t + 1 < NT) QKV_STAGE(cur ^ 1, (t + 1) << 6);
#pragma unroll
    for (int ks = 0; ks < 2; ks++) {
      const int rc = ((ks * 4 + lgrp) ^ (lrow & 7)) * 8;
      short8 af[8], bfr[4];
#pragma unroll
      for (int i = 0; i < 8; i++)
        af[i] = *(const short8*)&As[cur][(wr + i * 16 + lrow) * 64 + rc];
#pragma unroll
      for (int j = 0; j < 4; j++)
        bfr[j] = *(const short8*)&Bs[cur][(wc + j * 16 + lrow) * 64 + rc];
      __builtin_amdgcn_s_setprio(1);
#pragma unroll
      for (int i = 0; i < 8; i++)
#pragma unroll
        for (int j = 0; j < 4; j++)
          acc[i][j] = __builtin_amdgcn_mfma_f32_16x16x32_bf16(af[i], bfr[j], acc[i][j], 0, 0, 0);
      __builtin_amdgcn_s_setprio(0);
    }
  }

#pragma unroll
  for (int i = 0; i < 8; i++) {
    int row0 = bm * 256 + wr + i * 16 + lgrp * 4;
#pragma unroll
    for (int j = 0; j < 4; j++) {
      int col = bn * 256 + wc + j * 16 + lrow;
      int which = col / 1280;  // uniform per block (1280 % 256 == 0)
      int cl = col - which * 1280;
      const float* bias = which == 0 ? b0 : (which == 1 ? b1 : b2);
      float bv = bias[cl];
      if (which == 2) {  // V^T: 4 consecutive seq rows pack into one 8B store
        ushort4 pk;
        pk.x = f2bf(acc[i][j][0] + bv);
        pk.y = f2bf(acc[i][j][1] + bv);
        pk.z = f2bf(acc[i][j][2] + bv);
        pk.w = f2bf(acc[i][j][3] + bv);
        *(ushort4*)(outVT + (long)cl * SEQ + row0) = pk;
      } else {  // Q/K head-major [h][s][80]
        int hh = cl / 80, d = cl - hh * 80;
        u16* o = (which == 0 ? outQ : outK) + ((long)hh * SEQ + row0) * 80 + d;
#pragma unroll
        for (int r = 0; r < 4; r++) o[r * 80] = f2bf(acc[i][j][r] + bv);
      }
    }
  }
}

// ------------- O-proj GEMM: 64x128 tile, BK=64, 8 waves (32x32 each) -------
__global__ __launch_bounds__(512) void gemm_oproj(
    const u16* __restrict__ A, const u16* __restrict__ B,
    const float* __restrict__ b0, float* __restrict__ outF) {
  __shared__ u16 As[2][64 * 64];
  __shared__ u16 Bs[2][128 * 64];
  const int K = DIM;
  const int tid = threadIdx.x;
  const int wave = tid >> 6, lane = tid & 63;
  const int lrow = lane & 15, lgrp = lane >> 4;
  const int wr = (wave >> 2) * 32, wc = (wave & 3) * 32;

  const int nwg = gridDim.x;  // 320, %8==0
  const int lid = blockIdx.x;
  const int wg = (lid & 7) * (nwg >> 3) + (lid >> 3);
  const int bm = wg & 31, bn = wg >> 5;  // 32 M-blocks, 10 N-blocks (bijective)

  const int rowA = tid >> 3;
  const int offA = ((tid & 7) ^ (rowA & 7)) * 8;
  int rowB[2], offB[2];
#pragma unroll
  for (int j = 0; j < 2; j++) {
    int cid = j * 512 + tid;
    rowB[j] = cid >> 3;
    offB[j] = ((cid & 7) ^ (rowB[j] & 7)) * 8;
  }
  const u16* Abase = A + (long)bm * 64 * K;
  const u16* Bbase = B + (long)bn * 128 * K;

  f32x4 acc[2][2] = {};
  const int NT = K >> 6;

#define OP_STAGE(buf, k0)                                                          \
  {                                                                                \
    GLOAD16(Abase + (long)rowA * K + (k0) + offA, &As[buf][(wave * 64) * 8]);      \
    _Pragma("unroll") for (int j = 0; j < 2; j++)                                  \
        GLOAD16(Bbase + (long)rowB[j] * K + (k0) + offB[j],                        \
                &Bs[buf][(j * 512 + wave * 64) * 8]);                              \
  }

  OP_STAGE(0, 0);

  for (int t = 0; t < NT; t++) {
    const int cur = t & 1;
    ACQUIRE();
    if (t + 1 < NT) OP_STAGE(cur ^ 1, (t + 1) << 6);
#pragma unroll
    for (int ks = 0; ks < 2; ks++) {
      const int rc = ((ks * 4 + lgrp) ^ (lrow & 7)) * 8;
      short8 af[2], bfr[2];
#pragma unroll
      for (int i = 0; i < 2; i++)
        af[i] = *(const short8*)&As[cur][(wr + i * 16 + lrow) * 64 + rc];
#pragma unroll
      for (int j = 0; j < 2; j++)
        bfr[j] = *(const short8*)&Bs[cur][(wc + j * 16 + lrow) * 64 + rc];
      __builtin_amdgcn_s_setprio(1);
#pragma unroll
      for (int i = 0; i < 2; i++)
#pragma unroll
        for (int j = 0; j < 2; j++)
          acc[i][j] = __builtin_amdgcn_mfma_f32_16x16x32_bf16(af[i], bfr[j], acc[i][j], 0, 0, 0);
      __builtin_amdgcn_s_setprio(0);
    }
  }

#pragma unroll
  for (int i = 0; i < 2; i++) {
    int row0 = bm * 64 + wr + i * 16 + lgrp * 4;
#pragma unroll
    for (int j = 0; j < 2; j++) {
      int col = bn * 128 + wc + j * 16 + lrow;
      float bv = b0[col];
#pragma unroll
      for (int r = 0; r < 4; r++)
        outF[(long)(row0 + r) * DIM + col] = acc[i][j][r] + bv;
    }
  }
}

// ---------------- RoPE (in place, head-major Q,K), ushort8-vectorized ------
__global__ void rope_kernel(u16* __restrict__ Q, u16* __restrict__ Kt,
                            const float* __restrict__ cosT,
                            const float* __restrict__ sinT) {
  int idx = blockIdx.x * 256 + threadIdx.x;
  if (idx >= NH * SEQ * 5) return;
  int jj = (idx % 5) * 8;
  int t = idx / 5;
  int s = t & (SEQ - 1);
  int h = t >> 11;
  long base = ((long)h * SEQ + s) * 80;

  float ca[8], sa[8], cb[8], sb[8];
#pragma unroll
  for (int k = 0; k < 8; k++) {
    ca[k] = cosT[s * HD + jj + k];
    sa[k] = sinT[s * HD + jj + k];
    cb[k] = cosT[s * HD + jj + 40 + k];
    sb[k] = sinT[s * HD + jj + 40 + k];
  }

  short8 qa = *(const short8*)(Q + base + jj);
  short8 qb = *(const short8*)(Q + base + jj + 40);
  short8 ka = *(const short8*)(Kt + base + jj);
  short8 kb8 = *(const short8*)(Kt + base + jj + 40);
  short8 oqa, oqb, oka, okb;
#pragma unroll
  for (int k = 0; k < 8; k++) {
    float q0 = bf2f((u16)qa[k]), q1 = bf2f((u16)qb[k]);
    oqa[k] = (short)f2bf(q0 * ca[k] - q1 * sa[k]);
    oqb[k] = (short)f2bf(q1 * cb[k] + q0 * sb[k]);
    float k0 = bf2f((u16)ka[k]), k1 = bf2f((u16)kb8[k]);
    oka[k] = (short)f2bf(k0 * ca[k] - k1 * sa[k]);
    okb[k] = (short)f2bf(k1 * cb[k] + k0 * sb[k]);
  }
  *(short8*)(Q + base + jj) = oqa;
  *(short8*)(Q + base + jj + 40) = oqb;
  *(short8*)(Kt + base + jj) = oka;
  *(short8*)(Kt + base + jj + 40) = okb;
}

// ------------- Flash attention: QBLK=128, KVBLK=128, 8 waves, 1-barrier ----
__global__ __launch_bounds__(512) void attn_kernel(
    const u16* __restrict__ Q, const u16* __restrict__ K,
    const u16* __restrict__ VT, u16* __restrict__ O, const int* __restrict__ cu) {
  // decode XCD-grouped flat id: u = (b&7)*32 + (b>>3); u = hg*4 + qt
  const int b = blockIdx.x;
  const int u = ((b & 7) << 5) + (b >> 3);
  const int qt = u & 3;
  const int hg = u >> 2;       // 0..63
  const int h = hg >> 2;       // 16 heads
  const int g = hg & 3;        // 4 segments
  const int s0 = cu[g], s1 = cu[g + 1];
  const int qbase = s0 + qt * 128;
  if (qbase >= s1) return;

  __shared__ u16 k_s[2][128 * 80];   // [key][d], 10 chunks/row, XOR-swz (c<8)
  __shared__ u16 vt_s[2][80 * 128];  // [d][key], 16 chunks/row, XOR-swz
  __shared__ u16 ps[8 * 16 * 128];   // per-wave P [qrow][key], swizzled

  const int tid = threadIdx.x;
  const int wave = tid >> 6, lane = tid & 63;
  const int lrow = lane & 15, lgrp = lane >> 4;

  const u16* Kh = K + (long)h * SEQ * 80;
  const u16* Vh = VT + (long)h * 80 * SEQ;

  int qrow = qbase + wave * 16 + lrow;
  const u16* qptr = Q + ((long)h * SEQ + qrow) * 80;
  short8 aq[3];
#pragma unroll
  for (int ks = 0; ks < 3; ks++) {
    short8 z = {};
    if (ks < 2 || lgrp < 2) z = *(const short8*)(qptr + ks * 32 + lgrp * 8);
    aq[ks] = z;
  }

  f32x4 o_acc[5] = {};
  float m_r = -1e30f, l_r = 0.f;
  const float scale = 0.11180339887498949f;  // 1/sqrt(80)

  const int nk = (s1 - s0 + 127) / 128;  // 4

#define STAGE_KV(buf, kb)                                                          \
  {                                                                                \
    _Pragma("unroll") for (int j = 0; j < 5; j++) {                                \
      int chunk = j * 512 + tid;                                                   \
      if (chunk < 1280) {                                                          \
        int krow = chunk / 10, c = chunk - krow * 10;                              \
        int cs = c < 8 ? (c ^ (krow & 7)) : c;                                     \
        GLOAD16(Kh + ((long)((kb) + krow)) * 80 + cs * 8,                          \
                &k_s[buf][(j * 512 + wave * 64) * 8]);                             \
      } else {                                                                     \
        int vc = chunk - 1280;                                                     \
        int d = vc >> 4, c = vc & 15;                                              \
        GLOAD16(Vh + (long)d * SEQ + (kb) + ((c ^ (d & 7)) * 8),                   \
                &vt_s[buf][(j * 512 + wave * 64 - 1280) * 8]);                     \
      }                                                                            \
    }                                                                              \
  }

  STAGE_KV(0, s0);

  for (int ck = 0; ck < nk; ck++) {
    const int kb = s0 + ck * 128;
    const int cur = ck & 1;
    ACQUIRE();  // cur staged everywhere; all waves done reading prev
    if (ck + 1 < nk) STAGE_KV(cur ^ 1, kb + 128);

    // S^T = K * Q^T
    f32x4 sa[8];
#pragma unroll
    for (int n = 0; n < 8; n++) sa[n] = (f32x4){0.f, 0.f, 0.f, 0.f};
#pragma unroll
    for (int n = 0; n < 8; n++) {
      int row = n * 16 + lrow;
      short8 kf0, kf1, kf2 = {};
      {
        int cl = (0 * 4 + lgrp) ^ (row & 7);
        kf0 = *(const short8*)&k_s[cur][row * 80 + cl * 8];
        cl = (1 * 4 + lgrp) ^ (row & 7);
        kf1 = *(const short8*)&k_s[cur][row * 80 + cl * 8];
        if (lgrp < 2) kf2 = *(const short8*)&k_s[cur][row * 80 + (8 + lgrp) * 8];
      }
      __builtin_amdgcn_s_setprio(1);
      sa[n] = __builtin_amdgcn_mfma_f32_16x16x32_bf16(kf0, aq[0], sa[n], 0, 0, 0);
      sa[n] = __builtin_amdgcn_mfma_f32_16x16x32_bf16(kf1, aq[1], sa[n], 0, 0, 0);
      sa[n] = __builtin_amdgcn_mfma_f32_16x16x32_bf16(kf2, aq[2], sa[n], 0, 0, 0);
      __builtin_amdgcn_s_setprio(0);
    }

    float pm = -1e30f;
    float pv[8][4];
#pragma unroll
    for (int n = 0; n < 8; n++)
#pragma unroll
      for (int r = 0; r < 4; r++) {
        float v = sa[n][r] * scale;
        pv[n][r] = v;
        pm = fmaxf(pm, v);
      }
    pm = fmaxf(pm, __shfl_xor(pm, 16));
    pm = fmaxf(pm, __shfl_xor(pm, 32));
    float mnew = fmaxf(m_r, pm);
    float sc = __expf(m_r - mnew);
    float ls = 0.f;
#pragma unroll
    for (int n = 0; n < 8; n++)
#pragma unroll
      for (int r = 0; r < 4; r++) {
        float e = __expf(pv[n][r] - mnew);
        pv[n][r] = e;
        ls += e;
      }
    ls += __shfl_xor(ls, 16);
    ls += __shfl_xor(ls, 32);
    l_r = l_r * sc + ls;
    m_r = mnew;

#pragma unroll
    for (int r = 0; r < 4; r++) {
      float scr = __shfl(sc, lgrp * 4 + r);
#pragma unroll
      for (int nf = 0; nf < 5; nf++) o_acc[nf][r] *= scr;
    }

#pragma unroll
    for (int n = 0; n < 8; n++) {
      uint2 w;
      w.x = (unsigned)f2bf(pv[n][0]) | ((unsigned)f2bf(pv[n][1]) << 16);
      w.y = (unsigned)f2bf(pv[n][2]) | ((unsigned)f2bf(pv[n][3]) << 16);
      int keybase = n * 16 + lgrp * 4;
      int cw = (keybase >> 3) ^ (lrow & 7);
      *(uint2*)&ps[wave * 2048 + lrow * 128 + cw * 8 + (keybase & 7)] = w;
    }

#pragma unroll
    for (int ks = 0; ks < 4; ks++) {
      int g8 = ks * 4 + lgrp;
      short8 pf = *(const short8*)&ps[wave * 2048 + lrow * 128 + (g8 ^ (lrow & 7)) * 8];
      __builtin_amdgcn_s_setprio(1);
#pragma unroll
      for (int nf = 0; nf < 5; nf++) {
        int d = nf * 16 + lrow;
        short8 vf = *(const short8*)&vt_s[cur][d * 128 + (g8 ^ (d & 7)) * 8];
        o_acc[nf] = __builtin_amdgcn_mfma_f32_16x16x32_bf16(pf, vf, o_acc[nf], 0, 0, 0);
      }
      __builtin_amdgcn_s_setprio(0);
    }
  }

#pragma unroll
  for (int r = 0; r < 4; r++) {
    float lr = __shfl(l_r, lgrp * 4 + r);
    float inv = 1.0f / lr;
    int row = qbase + wave * 16 + lgrp * 4 + r;
#pragma unroll
    for (int nf = 0; nf < 5; nf++)
      O[(long)row * DIM + h * HD + nf * 16 + lrow] = f2bf(o_acc[nf][r] * inv);
  }
}

extern "C" void kernel_launch(void* const* d_in, const int* in_sizes, int n_in,
                              void* d_out, int out_size, void* d_ws, size_t ws_size,
                              hipStream_t stream) {
  const float* hs = (const float*)d_in[0];
  const float* Wq = (const float*)d_in[1];
  const float* bq = (const float*)d_in[2];
  const float* Wk = (const float*)d_in[3];
  const float* bk = (const float*)d_in[4];
  const float* Wv = (const float*)d_in[5];
  const float* bv = (const float*)d_in[6];
  const float* Wo = (const float*)d_in[7];
  const float* bo = (const float*)d_in[8];
  const float* cosT = (const float*)d_in[9];
  const float* sinT = (const float*)d_in[10];
  const int* cu = (const int*)d_in[11];

  char* ws = (char*)d_ws;
  u16* hs_b = (u16*)(ws);
  u16* wq_b = (u16*)(ws + 5242880);   // [Wq;Wk;Wv;Wo] contiguous bf16
  u16* wo_b = (u16*)(ws + 15073280);
  u16* q_b  = (u16*)(ws + 18350080);  // head-major [16][2048][80]
  u16* k_b  = (u16*)(ws + 23592960);  // head-major
  u16* vt_g = (u16*)(ws + 28835840);  // V^T [1280][2048]
  u16* ao_b = (u16*)(ws + 34078720);  // [2048][1280]

  const int nh = SEQ * DIM;
  const int nw = DIM * DIM;
  cvt5<<<dim3(nh / 1024, 5), 256, 0, stream>>>(hs, Wq, Wk, Wv, Wo, hs_b, wq_b, nh, nw);

  // merged QKV GEMM: 256x256 tiles, grid = 8*15 = 120 blocks, 512 threads
  gemm_qkv128<<<(SEQ / 256) * (3 * DIM / 256), 512, 0, stream>>>(
      hs_b, wq_b, bq, bk, bv, q_b, k_b, vt_g);

  rope_kernel<<<(NH * SEQ * 5 + 255) / 256, 256, 0, stream>>>(q_b, k_b, cosT, sinT);

  // attention: 256 blocks, 512 threads, XCD-grouped flat grid
  attn_kernel<<<NH * 4 * (SEQ / 4 / 128), 512, 0, stream>>>(q_b, k_b, vt_g, ao_b, cu);

  // O-proj: grid = 32*10 = 320 blocks, 512 threads
  gemm_oproj<<<(SEQ / 64) * (DIM / 128), 512, 0, stream>>>(ao_b, wo_b, bo,
                                                           (float*)d_out);
}

// Round 16
// 81.339 us; speedup vs baseline: 1.2805x; 1.2805x over previous
//
#include <hip/hip_runtime.h>

#define SEQ 2048
#define DIM 1280
#define NH 16
#define HD 80

typedef __attribute__((ext_vector_type(8))) short short8;
typedef __attribute__((ext_vector_type(4))) float f32x4;
typedef unsigned short u16;

__device__ inline u16 f2bf(float f) {
  unsigned u = __builtin_bit_cast(unsigned, f);
  u += 0x7FFFu + ((u >> 16) & 1u);
  return (u16)(u >> 16);
}
__device__ inline float bf2f(u16 h) {
  unsigned u = ((unsigned)h) << 16;
  return __builtin_bit_cast(float, u);
}

// async global->LDS, 16B per lane, dest = wave-uniform base + lane*16
#define GLOAD16(gsrc, ldst)                                                          \
  __builtin_amdgcn_global_load_lds((const __attribute__((address_space(1))) unsigned*)(gsrc), \
                                   (__attribute__((address_space(3))) unsigned*)(ldst), 16, 0, 0)

// acquire: own in-flight loads drained (aged one full step -> ~free), then
// block-wide barrier; sched_barrier pins everything below it.
#define ACQUIRE()                                  \
  asm volatile("s_waitcnt vmcnt(0)" ::: "memory"); \
  __builtin_amdgcn_s_barrier();                    \
  __builtin_amdgcn_sched_barrier(0)

// ---------------- all f32 -> bf16 conversions in one launch ----------------
__global__ void cvt5(const float* __restrict__ s0, const float* __restrict__ s1,
                     const float* __restrict__ s2, const float* __restrict__ s3,
                     const float* __restrict__ s4, u16* __restrict__ hs_b,
                     u16* __restrict__ w_b, int nh, int nw) {
  int y = blockIdx.y;
  const float* src = y == 0 ? s0 : (y == 1 ? s1 : (y == 2 ? s2 : (y == 3 ? s3 : s4)));
  int n = y == 0 ? nh : nw;
  u16* dst = y == 0 ? hs_b : w_b + (long)(y - 1) * nw;
  int i = (blockIdx.x * 256 + threadIdx.x) * 4;
  if (i >= n) return;
  float4 v = *(const float4*)(src + i);
  ushort4 pk;
  pk.x = f2bf(v.x); pk.y = f2bf(v.y); pk.z = f2bf(v.z); pk.w = f2bf(v.w);
  *(ushort4*)(dst + i) = pk;
}

// ------------- QKV GEMM: 128x128 tile, BK=64, 8 waves (64x32 each, 4x2) -----
// FROZEN at R10-best: 1-barrier/step protocol + setprio.
__global__ __launch_bounds__(512) void gemm_qkv128(
    const u16* __restrict__ A, const u16* __restrict__ B,
    const float* __restrict__ b0, const float* __restrict__ b1,
    const float* __restrict__ b2, u16* __restrict__ outQ, u16* __restrict__ outK,
    u16* __restrict__ outVT) {
  __shared__ u16 As[2][128 * 64];
  __shared__ u16 Bs[2][128 * 64];
  const int K = DIM;
  const int tid = threadIdx.x;
  const int wave = tid >> 6, lane = tid & 63;
  const int lrow = lane & 15, lgrp = lane >> 4;
  const int wr = (wave >> 2) * 64, wc = (wave & 3) * 32;

  const int nwg = gridDim.x;  // 480, %8==0
  const int lid = blockIdx.x;
  const int wg = (lid & 7) * (nwg >> 3) + (lid >> 3);
  const int bm = wg & 15, bn = wg >> 4;  // 16 M-blocks, 30 N-blocks

  int rowS[2], offS[2];
#pragma unroll
  for (int j = 0; j < 2; j++) {
    int cid = j * 512 + tid;
    rowS[j] = cid >> 3;
    offS[j] = ((cid & 7) ^ (rowS[j] & 7)) * 8;
  }
  const u16* Abase = A + (long)bm * 128 * K;
  const u16* Bbase = B + (long)bn * 128 * K;

  f32x4 acc[4][2] = {};
  const int NT = K >> 6;  // 20

#define QKV_STAGE(buf, k0)                                                         \
  {                                                                                \
    _Pragma("unroll") for (int j = 0; j < 2; j++)                                  \
        GLOAD16(Abase + (long)rowS[j] * K + (k0) + offS[j],                        \
                &As[buf][(j * 512 + wave * 64) * 8]);                              \
    _Pragma("unroll") for (int j = 0; j < 2; j++)                                  \
        GLOAD16(Bbase + (long)rowS[j] * K + (k0) + offS[j],                        \
                &Bs[buf][(j * 512 + wave * 64) * 8]);                              \
  }

  QKV_STAGE(0, 0);

  for (int t = 0; t < NT; t++) {
    const int cur = t & 1;
    ACQUIRE();  // cur's loads landed everywhere; prev reads done everywhere
    if (t + 1 < NT) QKV_STAGE(cur ^ 1, (t + 1) << 6);
#pragma unroll
    for (int ks = 0; ks < 2; ks++) {
      const int rc = ((ks * 4 + lgrp) ^ (lrow & 7)) * 8;
      short8 af[4], bfr[2];
#pragma unroll
      for (int i = 0; i < 4; i++)
        af[i] = *(const short8*)&As[cur][(wr + i * 16 + lrow) * 64 + rc];
#pragma unroll
      for (int j = 0; j < 2; j++)
        bfr[j] = *(const short8*)&Bs[cur][(wc + j * 16 + lrow) * 64 + rc];
      __builtin_amdgcn_s_setprio(1);
#pragma unroll
      for (int i = 0; i < 4; i++)
#pragma unroll
        for (int j = 0; j < 2; j++)
          acc[i][j] = __builtin_amdgcn_mfma_f32_16x16x32_bf16(af[i], bfr[j], acc[i][j], 0, 0, 0);
      __builtin_amdgcn_s_setprio(0);
    }
  }

#pragma unroll
  for (int i = 0; i < 4; i++) {
    int row0 = bm * 128 + wr + i * 16 + lgrp * 4;
#pragma unroll
    for (int j = 0; j < 2; j++) {
      int col = bn * 128 + wc + j * 16 + lrow;
      int which = col / 1280;  // uniform per block (bn-decided)
      int cl = col - which * 1280;
      const float* bias = which == 0 ? b0 : (which == 1 ? b1 : b2);
      float bv = bias[cl];
      if (which == 2) {  // V^T: 4 consecutive seq rows pack into one 8B store
        ushort4 pk;
        pk.x = f2bf(acc[i][j][0] + bv);
        pk.y = f2bf(acc[i][j][1] + bv);
        pk.z = f2bf(acc[i][j][2] + bv);
        pk.w = f2bf(acc[i][j][3] + bv);
        *(ushort4*)(outVT + (long)cl * SEQ + row0) = pk;
      } else {  // Q/K head-major [h][s][80]
        int hh = cl / 80, d = cl - hh * 80;
        u16* o = (which == 0 ? outQ : outK) + ((long)hh * SEQ + row0) * 80 + d;
#pragma unroll
        for (int r = 0; r < 4; r++) o[r * 80] = f2bf(acc[i][j][r] + bv);
      }
    }
  }
}

// ------------- O-proj GEMM: 64x128 tile, BK=64, 8 waves (32x32 each) -------
__global__ __launch_bounds__(512) void gemm_oproj(
    const u16* __restrict__ A, const u16* __restrict__ B,
    const float* __restrict__ b0, float* __restrict__ outF) {
  __shared__ u16 As[2][64 * 64];
  __shared__ u16 Bs[2][128 * 64];
  const int K = DIM;
  const int tid = threadIdx.x;
  const int wave = tid >> 6, lane = tid & 63;
  const int lrow = lane & 15, lgrp = lane >> 4;
  const int wr = (wave >> 2) * 32, wc = (wave & 3) * 32;

  const int nwg = gridDim.x;  // 320, %8==0
  const int lid = blockIdx.x;
  const int wg = (lid & 7) * (nwg >> 3) + (lid >> 3);
  const int bm = wg & 31, bn = wg >> 5;  // 32 M-blocks, 10 N-blocks (bijective)

  const int rowA = tid >> 3;
  const int offA = ((tid & 7) ^ (rowA & 7)) * 8;
  int rowB[2], offB[2];
#pragma unroll
  for (int j = 0; j < 2; j++) {
    int cid = j * 512 + tid;
    rowB[j] = cid >> 3;
    offB[j] = ((cid & 7) ^ (rowB[j] & 7)) * 8;
  }
  const u16* Abase = A + (long)bm * 64 * K;
  const u16* Bbase = B + (long)bn * 128 * K;

  f32x4 acc[2][2] = {};
  const int NT = K >> 6;

#define OP_STAGE(buf, k0)                                                          \
  {                                                                                \
    GLOAD16(Abase + (long)rowA * K + (k0) + offA, &As[buf][(wave * 64) * 8]);      \
    _Pragma("unroll") for (int j = 0; j < 2; j++)                                  \
        GLOAD16(Bbase + (long)rowB[j] * K + (k0) + offB[j],                        \
                &Bs[buf][(j * 512 + wave * 64) * 8]);                              \
  }

  OP_STAGE(0, 0);

  for (int t = 0; t < NT; t++) {
    const int cur = t & 1;
    ACQUIRE();
    if (t + 1 < NT) OP_STAGE(cur ^ 1, (t + 1) << 6);
#pragma unroll
    for (int ks = 0; ks < 2; ks++) {
      const int rc = ((ks * 4 + lgrp) ^ (lrow & 7)) * 8;
      short8 af[2], bfr[2];
#pragma unroll
      for (int i = 0; i < 2; i++)
        af[i] = *(const short8*)&As[cur][(wr + i * 16 + lrow) * 64 + rc];
#pragma unroll
      for (int j = 0; j < 2; j++)
        bfr[j] = *(const short8*)&Bs[cur][(wc + j * 16 + lrow) * 64 + rc];
      __builtin_amdgcn_s_setprio(1);
#pragma unroll
      for (int i = 0; i < 2; i++)
#pragma unroll
        for (int j = 0; j < 2; j++)
          acc[i][j] = __builtin_amdgcn_mfma_f32_16x16x32_bf16(af[i], bfr[j], acc[i][j], 0, 0, 0);
      __builtin_amdgcn_s_setprio(0);
    }
  }

#pragma unroll
  for (int i = 0; i < 2; i++) {
    int row0 = bm * 64 + wr + i * 16 + lgrp * 4;
#pragma unroll
    for (int j = 0; j < 2; j++) {
      int col = bn * 128 + wc + j * 16 + lrow;
      float bv = b0[col];
#pragma unroll
      for (int r = 0; r < 4; r++)
        outF[(long)(row0 + r) * DIM + col] = acc[i][j][r] + bv;
    }
  }
}

// ---------------- RoPE (in place, head-major Q,K), ushort8-vectorized ------
__global__ void rope_kernel(u16* __restrict__ Q, u16* __restrict__ Kt,
                            const float* __restrict__ cosT,
                            const float* __restrict__ sinT) {
  int idx = blockIdx.x * 256 + threadIdx.x;
  if (idx >= NH * SEQ * 5) return;
  int jj = (idx % 5) * 8;
  int t = idx / 5;
  int s = t & (SEQ - 1);
  int h = t >> 11;
  long base = ((long)h * SEQ + s) * 80;

  float ca[8], sa[8], cb[8], sb[8];
#pragma unroll
  for (int k = 0; k < 8; k++) {
    ca[k] = cosT[s * HD + jj + k];
    sa[k] = sinT[s * HD + jj + k];
    cb[k] = cosT[s * HD + jj + 40 + k];
    sb[k] = sinT[s * HD + jj + 40 + k];
  }

  short8 qa = *(const short8*)(Q + base + jj);
  short8 qb = *(const short8*)(Q + base + jj + 40);
  short8 ka = *(const short8*)(Kt + base + jj);
  short8 kb8 = *(const short8*)(Kt + base + jj + 40);
  short8 oqa, oqb, oka, okb;
#pragma unroll
  for (int k = 0; k < 8; k++) {
    float q0 = bf2f((u16)qa[k]), q1 = bf2f((u16)qb[k]);
    oqa[k] = (short)f2bf(q0 * ca[k] - q1 * sa[k]);
    oqb[k] = (short)f2bf(q1 * cb[k] + q0 * sb[k]);
    float k0 = bf2f((u16)ka[k]), k1 = bf2f((u16)kb8[k]);
    oka[k] = (short)f2bf(k0 * ca[k] - k1 * sa[k]);
    okb[k] = (short)f2bf(k1 * cb[k] + k0 * sb[k]);
  }
  *(short8*)(Q + base + jj) = oqa;
  *(short8*)(Q + base + jj + 40) = oqb;
  *(short8*)(Kt + base + jj) = oka;
  *(short8*)(Kt + base + jj + 40) = okb;
}

// ------------- Flash attention: QBLK=128, KVBLK=128, 8 waves, 1-barrier ----
// R10-best config (ps-LDS relayout; 256 blocks, XCD-grouped).
__global__ __launch_bounds__(512) void attn_kernel(
    const u16* __restrict__ Q, const u16* __restrict__ K,
    const u16* __restrict__ VT, u16* __restrict__ O, const int* __restrict__ cu) {
  // decode XCD-grouped flat id: u = (b&7)*32 + (b>>3); u = hg*4 + qt
  const int b = blockIdx.x;
  const int u = ((b & 7) << 5) + (b >> 3);
  const int qt = u & 3;
  const int hg = u >> 2;       // 0..63
  const int h = hg >> 2;       // 16 heads
  const int g = hg & 3;        // 4 segments
  const int s0 = cu[g], s1 = cu[g + 1];
  const int qbase = s0 + qt * 128;
  if (qbase >= s1) return;

  __shared__ u16 k_s[2][128 * 80];   // [key][d], 10 chunks/row, XOR-swz (c<8)
  __shared__ u16 vt_s[2][80 * 128];  // [d][key], 16 chunks/row, XOR-swz
  __shared__ u16 ps[8 * 16 * 128];   // per-wave P [qrow][key], swizzled

  const int tid = threadIdx.x;
  const int wave = tid >> 6, lane = tid & 63;
  const int lrow = lane & 15, lgrp = lane >> 4;

  const u16* Kh = K + (long)h * SEQ * 80;
  const u16* Vh = VT + (long)h * 80 * SEQ;

  int qrow = qbase + wave * 16 + lrow;
  const u16* qptr = Q + ((long)h * SEQ + qrow) * 80;
  short8 aq[3];
#pragma unroll
  for (int ks = 0; ks < 3; ks++) {
    short8 z = {};
    if (ks < 2 || lgrp < 2) z = *(const short8*)(qptr + ks * 32 + lgrp * 8);
    aq[ks] = z;
  }

  f32x4 o_acc[5] = {};
  float m_r = -1e30f, l_r = 0.f;
  const float scale = 0.11180339887498949f;  // 1/sqrt(80)

  const int nk = (s1 - s0 + 127) / 128;  // 4

#define STAGE_KV(buf, kb)                                                          \
  {                                                                                \
    _Pragma("unroll") for (int j = 0; j < 5; j++) {                                \
      int chunk = j * 512 + tid;                                                   \
      if (chunk < 1280) {                                                          \
        int krow = chunk / 10, c = chunk - krow * 10;                              \
        int cs = c < 8 ? (c ^ (krow & 7)) : c;                                     \
        GLOAD16(Kh + ((long)((kb) + krow)) * 80 + cs * 8,                          \
                &k_s[buf][(j * 512 + wave * 64) * 8]);                             \
      } else {                                                                     \
        int vc = chunk - 1280;                                                     \
        int d = vc >> 4, c = vc & 15;                                              \
        GLOAD16(Vh + (long)d * SEQ + (kb) + ((c ^ (d & 7)) * 8),                   \
                &vt_s[buf][(j * 512 + wave * 64 - 1280) * 8]);                     \
      }                                                                            \
    }                                                                              \
  }

  STAGE_KV(0, s0);

  for (int ck = 0; ck < nk; ck++) {
    const int kb = s0 + ck * 128;
    const int cur = ck & 1;
    ACQUIRE();  // cur staged everywhere; all waves done reading prev
    if (ck + 1 < nk) STAGE_KV(cur ^ 1, kb + 128);

    // S^T = K * Q^T
    f32x4 sa[8];
#pragma unroll
    for (int n = 0; n < 8; n++) sa[n] = (f32x4){0.f, 0.f, 0.f, 0.f};
#pragma unroll
    for (int n = 0; n < 8; n++) {
      int row = n * 16 + lrow;
      short8 kf0, kf1, kf2 = {};
      {
        int cl = (0 * 4 + lgrp) ^ (row & 7);
        kf0 = *(const short8*)&k_s[cur][row * 80 + cl * 8];
        cl = (1 * 4 + lgrp) ^ (row & 7);
        kf1 = *(const short8*)&k_s[cur][row * 80 + cl * 8];
        if (lgrp < 2) kf2 = *(const short8*)&k_s[cur][row * 80 + (8 + lgrp) * 8];
      }
      __builtin_amdgcn_s_setprio(1);
      sa[n] = __builtin_amdgcn_mfma_f32_16x16x32_bf16(kf0, aq[0], sa[n], 0, 0, 0);
      sa[n] = __builtin_amdgcn_mfma_f32_16x16x32_bf16(kf1, aq[1], sa[n], 0, 0, 0);
      sa[n] = __builtin_amdgcn_mfma_f32_16x16x32_bf16(kf2, aq[2], sa[n], 0, 0, 0);
      __builtin_amdgcn_s_setprio(0);
    }

    float pm = -1e30f;
    float pv[8][4];
#pragma unroll
    for (int n = 0; n < 8; n++)
#pragma unroll
      for (int r = 0; r < 4; r++) {
        float v = sa[n][r] * scale;
        pv[n][r] = v;
        pm = fmaxf(pm, v);
      }
    pm = fmaxf(pm, __shfl_xor(pm, 16));
    pm = fmaxf(pm, __shfl_xor(pm, 32));
    float mnew = fmaxf(m_r, pm);
    float sc = __expf(m_r - mnew);
    float ls = 0.f;
#pragma unroll
    for (int n = 0; n < 8; n++)
#pragma unroll
      for (int r = 0; r < 4; r++) {
        float e = __expf(pv[n][r] - mnew);
        pv[n][r] = e;
        ls += e;
      }
    ls += __shfl_xor(ls, 16);
    ls += __shfl_xor(ls, 32);
    l_r = l_r * sc + ls;
    m_r = mnew;

#pragma unroll
    for (int r = 0; r < 4; r++) {
      float scr = __shfl(sc, lgrp * 4 + r);
#pragma unroll
      for (int nf = 0; nf < 5; nf++) o_acc[nf][r] *= scr;
    }

#pragma unroll
    for (int n = 0; n < 8; n++) {
      uint2 w;
      w.x = (unsigned)f2bf(pv[n][0]) | ((unsigned)f2bf(pv[n][1]) << 16);
      w.y = (unsigned)f2bf(pv[n][2]) | ((unsigned)f2bf(pv[n][3]) << 16);
      int keybase = n * 16 + lgrp * 4;
      int cw = (keybase >> 3) ^ (lrow & 7);
      *(uint2*)&ps[wave * 2048 + lrow * 128 + cw * 8 + (keybase & 7)] = w;
    }

#pragma unroll
    for (int ks = 0; ks < 4; ks++) {
      int g8 = ks * 4 + lgrp;
      short8 pf = *(const short8*)&ps[wave * 2048 + lrow * 128 + (g8 ^ (lrow & 7)) * 8];
      __builtin_amdgcn_s_setprio(1);
#pragma unroll
      for (int nf = 0; nf < 5; nf++) {
        int d = nf * 16 + lrow;
        short8 vf = *(const short8*)&vt_s[cur][d * 128 + (g8 ^ (d & 7)) * 8];
        o_acc[nf] = __builtin_amdgcn_mfma_f32_16x16x32_bf16(pf, vf, o_acc[nf], 0, 0, 0);
      }
      __builtin_amdgcn_s_setprio(0);
    }
  }

#pragma unroll
  for (int r = 0; r < 4; r++) {
    float lr = __shfl(l_r, lgrp * 4 + r);
    float inv = 1.0f / lr;
    int row = qbase + wave * 16 + lgrp * 4 + r;
#pragma unroll
    for (int nf = 0; nf < 5; nf++)
      O[(long)row * DIM + h * HD + nf * 16 + lrow] = f2bf(o_acc[nf][r] * inv);
  }
}

extern "C" void kernel_launch(void* const* d_in, const int* in_sizes, int n_in,
                              void* d_out, int out_size, void* d_ws, size_t ws_size,
                              hipStream_t stream) {
  const float* hs = (const float*)d_in[0];
  const float* Wq = (const float*)d_in[1];
  const float* bq = (const float*)d_in[2];
  const float* Wk = (const float*)d_in[3];
  const float* bk = (const float*)d_in[4];
  const float* Wv = (const float*)d_in[5];
  const float* bv = (const float*)d_in[6];
  const float* Wo = (const float*)d_in[7];
  const float* bo = (const float*)d_in[8];
  const float* cosT = (const float*)d_in[9];
  const float* sinT = (const float*)d_in[10];
  const int* cu = (const int*)d_in[11];

  char* ws = (char*)d_ws;
  u16* hs_b = (u16*)(ws);
  u16* wq_b = (u16*)(ws + 5242880);   // [Wq;Wk;Wv;Wo] contiguous bf16
  u16* wo_b = (u16*)(ws + 15073280);
  u16* q_b  = (u16*)(ws + 18350080);  // head-major [16][2048][80]
  u16* k_b  = (u16*)(ws + 23592960);  // head-major
  u16* vt_g = (u16*)(ws + 28835840);  // V^T [1280][2048]
  u16* ao_b = (u16*)(ws + 34078720);  // [2048][1280]

  const int nh = SEQ * DIM;
  const int nw = DIM * DIM;
  cvt5<<<dim3(nh / 1024, 5), 256, 0, stream>>>(hs, Wq, Wk, Wv, Wo, hs_b, wq_b, nh, nw);

  // merged QKV GEMM: grid = 16*30 = 480 blocks, 512 threads (8 waves, 4x2)
  gemm_qkv128<<<(SEQ / 128) * (3 * DIM / 128), 512, 0, stream>>>(
      hs_b, wq_b, bq, bk, bv, q_b, k_b, vt_g);

  rope_kernel<<<(NH * SEQ * 5 + 255) / 256, 256, 0, stream>>>(q_b, k_b, cosT, sinT);

  // attention: 256 blocks, 512 threads, XCD-grouped flat grid
  attn_kernel<<<NH * 4 * (SEQ / 4 / 128), 512, 0, stream>>>(q_b, k_b, vt_g, ao_b, cu);

  // O-proj: grid = 32*10 = 320 blocks, 512 threads
  gemm_oproj<<<(SEQ / 64) * (DIM / 128), 512, 0, stream>>>(ao_b, wo_b, bo,
                                                           (float*)d_out);
}